// Round 6
// baseline (9617.533 us; speedup 1.0000x reference)
//
#include <hip/hip_runtime.h>
#include <math.h>

// Problem dims
#define TT 2048
#define VV 1024
#define HH 2048
#define SS (VV + HH)        // 3072: row stride of Wf_w / Wb_w

// Geometry: 256 WGs x 512 threads, one WG per CU (forced by ~140KB LDS).
#define NWGD 128            // workgroups per direction
#define BTH  512            // threads per workgroup (8 waves)
#define UPW  16             // hidden units per wg
#define RPG  4              // rows per thread (register blocking)
#define RGN  16             // rowgroups (RGN*RPG = 64 gate rows per wg)
#define KSL  32             // k-slices per row
#define KPT  64             // k-elements per thread per row
#define CHR  16             // float4 chunks per row per thread (KPT/4)
#define RCHR 12             // chunks per row in VGPRs (4 rows x 12 x 4 = 192 regs)
#define LCHR 4              // chunks per row in LDS (4 rows x 4 x 16B x 512 thr = 128KB)

static_assert(NWGD * UPW == HH, "unit coverage");
static_assert(RGN * KSL == BTH, "thread coverage");
static_assert(KSL * KPT == HH, "k coverage");
static_assert(RCHR + LCHR == CHR, "chunk split");

// Barrier area layout (uints), per direction at bar + dir*2048:
//   leaf l (l<8): +l*64 ; root: +8*64 ; flag f (f<8): +(9+f)*64
#define BAR_UINTS_PER_DIR 2048

__device__ __forceinline__ float sigmoidf_(float x) {
    return 1.0f / (1.0f + __expf(-x));
}

__global__ __launch_bounds__(BTH, 1)
void lstm_kernel(const float* __restrict__ Wf, const float* __restrict__ bfv,
                 const float* __restrict__ Wb, const float* __restrict__ bbv,
                 const int* __restrict__ cidx,
                 float* __restrict__ hsf, float* __restrict__ hsb,
                 unsigned* __restrict__ bar)
{
    const int wg   = blockIdx.x;
    const int dir  = wg >> 7;            // 0 fwd, 1 bwd
    const int w    = wg & (NWGD - 1);
    const int tid  = threadIdx.x;
    const int rg   = tid >> 5;           // rowgroup 0..15 (4 rows each)
    const int ks   = tid & (KSL - 1);    // k-slice 0..31 (64 k each)
    const int g    = rg >> 2;            // gate 0..3
    const int ub   = 4 * (rg & 3);       // unit base 0,4,8,12
    const int jj   = ks & 3;             // which of my 4 rows I finalize (ks<4)

    const float* W    = dir ? Wb : Wf;
    const float* bias = dir ? bbv : bfv;
    float* hs         = dir ? hsb : hsf;
    unsigned* base    = bar + dir * BAR_UINTS_PER_DIR;

    const int unit0 = w * UPW + ub;                       // first of my 4 units
    // finalize-lane data (valid for ks<4): row = g*HH + unit0 + jj
    const float* growm = W + (size_t)(g * HH + unit0 + jj) * SS;
    const float  bm    = bias[g * HH + unit0 + jj];

    // LDS: weights [row_j*LCHR + c][tid] float4 (lane-sequential, conflict-free),
    // h padded so slice starts hit distinct bank groups (float4 idx 17*ks).
    __shared__ float4 wl4[RPG * LCHR * BTH];              // 128 KB
    __shared__ float4 hl4[(HH + 4 * (HH / 64)) / 4];      // 2176 floats = 8.5 KB
    __shared__ float  glds[4][UPW];
    __shared__ float  cst[UPW];

    // ---- one-time: weight slab -> VGPRs + LDS ----
    float4 wr[RPG][RCHR];
    #pragma unroll
    for (int j = 0; j < RPG; ++j) {
        const float* rbase = W + (size_t)(g * HH + unit0 + j) * SS + VV + ks * KPT;
        #pragma unroll
        for (int c = 0; c < RCHR; ++c)
            wr[j][c] = *reinterpret_cast<const float4*>(rbase + 4 * c);
        #pragma unroll
        for (int c = 0; c < LCHR; ++c)
            wl4[(j * LCHR + c) * BTH + tid] =
                *reinterpret_cast<const float4*>(rbase + 4 * (RCHR + c));
    }

    if (tid < UPW) cst[tid] = 0.0f;
    __syncthreads();

    for (int s = 0; s < TT; ++s) {
        const int t  = dir ? (TT - 1 - s) : s;
        const int xt = cidx[t];
        float gx = 0.0f;
        if (ks < 4) gx = growm[xt];      // one-hot gather (exact fp32, L2/L3-hot)

        // ---- stage h_prev into LDS (agent-coherent loads, 4 floats/thread) ----
        {
            const int p4 = tid + (tid >> 4);              // padded float4 index
            if (s == 0) {
                hl4[p4] = make_float4(0.f, 0.f, 0.f, 0.f);
            } else {
                const int tprev = dir ? (t + 1) : (t - 1);
                const float* hsrc = hs + (size_t)tprev * HH + 4 * tid;
                float4 hv;
                hv.x = __hip_atomic_load(hsrc,     __ATOMIC_RELAXED, __HIP_MEMORY_SCOPE_AGENT);
                hv.y = __hip_atomic_load(hsrc + 1, __ATOMIC_RELAXED, __HIP_MEMORY_SCOPE_AGENT);
                hv.z = __hip_atomic_load(hsrc + 2, __ATOMIC_RELAXED, __HIP_MEMORY_SCOPE_AGENT);
                hv.w = __hip_atomic_load(hsrc + 3, __ATOMIC_RELAXED, __HIP_MEMORY_SCOPE_AGENT);
                hl4[p4] = hv;
            }
        }
        __syncthreads();

        // ---- recurrent dot: 4 rows x 64 k; each h-read feeds 16 FMAs ----
        float a0 = 0.f, a1 = 0.f, a2 = 0.f, a3 = 0.f;
        const int hb = 17 * ks;                           // padded float4 base
        #pragma unroll
        for (int c = 0; c < CHR; ++c) {
            const float4 hv = hl4[hb + c];
            float4 w0, w1, w2, w3;
            if (c < RCHR) {
                w0 = wr[0][c]; w1 = wr[1][c]; w2 = wr[2][c]; w3 = wr[3][c];
            } else {
                w0 = wl4[(0 * LCHR + (c - RCHR)) * BTH + tid];
                w1 = wl4[(1 * LCHR + (c - RCHR)) * BTH + tid];
                w2 = wl4[(2 * LCHR + (c - RCHR)) * BTH + tid];
                w3 = wl4[(3 * LCHR + (c - RCHR)) * BTH + tid];
            }
            a0 = fmaf(w0.x, hv.x, a0); a0 = fmaf(w0.y, hv.y, a0);
            a0 = fmaf(w0.z, hv.z, a0); a0 = fmaf(w0.w, hv.w, a0);
            a1 = fmaf(w1.x, hv.x, a1); a1 = fmaf(w1.y, hv.y, a1);
            a1 = fmaf(w1.z, hv.z, a1); a1 = fmaf(w1.w, hv.w, a1);
            a2 = fmaf(w2.x, hv.x, a2); a2 = fmaf(w2.y, hv.y, a2);
            a2 = fmaf(w2.z, hv.z, a2); a2 = fmaf(w2.w, hv.w, a2);
            a3 = fmaf(w3.x, hv.x, a3); a3 = fmaf(w3.y, hv.y, a3);
            a3 = fmaf(w3.z, hv.z, a3); a3 = fmaf(w3.w, hv.w, a3);
        }
        // butterfly over the 32 k-slices (stays within each 32-lane half)
        #pragma unroll
        for (int off = 1; off < KSL; off <<= 1) {
            a0 += __shfl_xor(a0, off, 64);
            a1 += __shfl_xor(a1, off, 64);
            a2 += __shfl_xor(a2, off, 64);
            a3 += __shfl_xor(a3, off, 64);
        }
        // lanes ks=0..3 finalize row jj (static select; no runtime array index)
        float v = a0;
        if (jj == 1) v = a1;
        else if (jj == 2) v = a2;
        else if (jj == 3) v = a3;
        if (ks < 4) glds[g][ub + jj] = v + gx + bm;
        __syncthreads();

        // ---- pointwise LSTM cell (16 units; wave 0) ----
        if (tid < UPW) {
            const float gi = sigmoidf_(glds[0][tid]);
            const float gf = sigmoidf_(glds[1][tid]);
            const float gg = tanhf(glds[2][tid]);
            const float go = sigmoidf_(glds[3][tid]);
            const float c  = gf * cst[tid] + gi * gg;
            cst[tid] = c;
            const float hv = go * tanhf(c);
            __hip_atomic_store(hs + (size_t)t * HH + w * UPW + tid, hv,
                               __ATOMIC_RELAXED, __HIP_MEMORY_SCOPE_AGENT);
        }
        __syncthreads();

        // ---- grid barrier: tree counters + replicated flags, all RELAXED ----
        if (tid == 0) {
            asm volatile("s_waitcnt vmcnt(0)" ::: "memory");  // drain wave-0 h stores
            unsigned* leaf = base + (w >> 4) * 64;
            const unsigned lo = __hip_atomic_fetch_add(leaf, 1u, __ATOMIC_RELAXED,
                                                       __HIP_MEMORY_SCOPE_AGENT);
            if (lo + 1 == 16u * (unsigned)(s + 1)) {
                unsigned* root = base + 8 * 64;
                const unsigned ro = __hip_atomic_fetch_add(root, 1u, __ATOMIC_RELAXED,
                                                           __HIP_MEMORY_SCOPE_AGENT);
                if (ro + 1 == 8u * (unsigned)(s + 1)) {
                    #pragma unroll
                    for (int f = 0; f < 8; ++f)
                        __hip_atomic_store(base + (9 + f) * 64, (unsigned)(s + 1),
                                           __ATOMIC_RELAXED, __HIP_MEMORY_SCOPE_AGENT);
                }
            }
            unsigned* fl = base + (9 + (w & 7)) * 64;
            while (__hip_atomic_load(fl, __ATOMIC_RELAXED, __HIP_MEMORY_SCOPE_AGENT)
                   < (unsigned)(s + 1)) {
                __builtin_amdgcn_s_sleep(2);
            }
            asm volatile("" ::: "memory");
        }
        __syncthreads();
    }
}

// out[t,v] = sum_j merged[t,j]*Wo[v,j] + bo[v],  merged = [hf | hb], K = 4096.
__global__ __launch_bounds__(256)
void out_gemm(const float* __restrict__ hsf, const float* __restrict__ hsb,
              const float* __restrict__ Wo, const float* __restrict__ bo,
              float* __restrict__ out)
{
    const int bn = blockIdx.x;
    const int bm = blockIdx.y;
    const int tid = threadIdx.x;
    const int tx = tid & 15, ty = tid >> 4;
    const int t0 = bm * 64, v0 = bn * 64;

    __shared__ float As[32][72];
    __shared__ float Bs[32][72];

    float acc[4][4] = {};

    const int rr = tid >> 2;
    const int kc = tid & 3;

    for (int kb = 0; kb < 2 * HH; kb += 32) {
        {
            const int k = kb + kc * 8;
            const float* asrc = (k < HH) ? (hsf + (size_t)(t0 + rr) * HH + k)
                                         : (hsb + (size_t)(t0 + rr) * HH + (k - HH));
            const float4 a0 = *reinterpret_cast<const float4*>(asrc);
            const float4 a1 = *reinterpret_cast<const float4*>(asrc + 4);
            const int kk = kc * 8;
            As[kk+0][rr]=a0.x; As[kk+1][rr]=a0.y; As[kk+2][rr]=a0.z; As[kk+3][rr]=a0.w;
            As[kk+4][rr]=a1.x; As[kk+5][rr]=a1.y; As[kk+6][rr]=a1.z; As[kk+7][rr]=a1.w;
            const float* bsrc = Wo + (size_t)(v0 + rr) * (2 * HH) + k;
            const float4 b0 = *reinterpret_cast<const float4*>(bsrc);
            const float4 b1 = *reinterpret_cast<const float4*>(bsrc + 4);
            Bs[kk+0][rr]=b0.x; Bs[kk+1][rr]=b0.y; Bs[kk+2][rr]=b0.z; Bs[kk+3][rr]=b0.w;
            Bs[kk+4][rr]=b1.x; Bs[kk+5][rr]=b1.y; Bs[kk+6][rr]=b1.z; Bs[kk+7][rr]=b1.w;
        }
        __syncthreads();
        #pragma unroll 8
        for (int kk = 0; kk < 32; ++kk) {
            const float4 av = *reinterpret_cast<const float4*>(&As[kk][ty * 4]);
            const float4 bv = *reinterpret_cast<const float4*>(&Bs[kk][tx * 4]);
            const float a[4] = {av.x, av.y, av.z, av.w};
            const float b[4] = {bv.x, bv.y, bv.z, bv.w};
            #pragma unroll
            for (int i2 = 0; i2 < 4; ++i2)
                #pragma unroll
                for (int j2 = 0; j2 < 4; ++j2)
                    acc[i2][j2] = fmaf(a[i2], b[j2], acc[i2][j2]);
        }
        __syncthreads();
    }
    #pragma unroll
    for (int i2 = 0; i2 < 4; ++i2) {
        const int t = t0 + ty * 4 + i2;
        #pragma unroll
        for (int j2 = 0; j2 < 4; ++j2) {
            const int v = v0 + tx * 4 + j2;
            out[(size_t)t * VV + v] = acc[i2][j2] + bo[v];
        }
    }
}

extern "C" void kernel_launch(void* const* d_in, const int* in_sizes, int n_in,
                              void* d_out, int out_size, void* d_ws, size_t ws_size,
                              hipStream_t stream)
{
    (void)in_sizes; (void)n_in; (void)out_size; (void)ws_size;

    const float* Wf  = (const float*)d_in[0];
    const float* bfv = (const float*)d_in[1];
    const float* Wb  = (const float*)d_in[2];
    const float* bbv = (const float*)d_in[3];
    const float* Wo  = (const float*)d_in[4];
    const float* bo  = (const float*)d_in[5];
    const int*   cid = (const int*)d_in[6];
    float* out = (float*)d_out;

    unsigned char* ws = (unsigned char*)d_ws;
    unsigned* bar = (unsigned*)ws;                         // 16 KiB barrier area
    float* hsf = (float*)(ws + 65536);                     // [T][H] fp32, 16 MiB
    float* hsb = hsf + (size_t)TT * HH;                    // [T][H] fp32, 16 MiB

    (void)hipMemsetAsync(bar, 0, 16384, stream);

    lstm_kernel<<<dim3(2 * NWGD), dim3(BTH), 0, stream>>>(Wf, bfv, Wb, bbv, cid,
                                                          hsf, hsb, bar);
    out_gemm<<<dim3(VV / 64, TT / 64), dim3(256), 0, stream>>>(hsf, hsb, Wo, bo, out);
}